// Round 1
// baseline (355.240 us; speedup 1.0000x reference)
//
#include <hip/hip_runtime.h>
#include <hip/hip_bf16.h>

#define EPSV 1e-5f

// ---------------- node pipeline ----------------
// h = relu((1 + gamma(cond)) * LN(node_feats @ W_film + b_film) + beta(cond))
// block: 192 threads (3 waves), tile of 16 nodes.
// waves 0-1 (t<128): gb[:,t] = cond @ W_cond + b_cond   (+1 on gamma cols)
// wave 2   (t>=128): h0[:,t-128] = nf @ W_film + b_film, then LN + FiLM + relu.
__global__ __launch_bounds__(192) void node_kernel(
    const float* __restrict__ node_feats, const float* __restrict__ cond,
    const float* __restrict__ W_cond, const float* __restrict__ b_cond,
    const float* __restrict__ W_film, const float* __restrict__ b_film,
    float* __restrict__ h, int N)
{
  __shared__ __align__(16) float cond_lds[16][256];
  __shared__ __align__(16) float nf_lds[16][128];
  __shared__ __align__(16) float gb_lds[16][128];
  const int t = threadIdx.x;
  const int n0 = blockIdx.x * 16;
  const int rows = min(16, N - n0);

  { // stage cond tile (16x256) and nf tile (16x128) as float4
    const float4* c4 = (const float4*)(cond + (size_t)n0 * 256);
    float4* sc = (float4*)&cond_lds[0][0];
    const int climit = rows * 64;
    for (int i = t; i < 16 * 64; i += 192)
      sc[i] = (i < climit) ? c4[i] : make_float4(0.f, 0.f, 0.f, 0.f);
    const float4* n4 = (const float4*)(node_feats + (size_t)n0 * 128);
    float4* sn = (float4*)&nf_lds[0][0];
    const int nlimit = rows * 32;
    for (int i = t; i < 16 * 32; i += 192)
      sn[i] = (i < nlimit) ? n4[i] : make_float4(0.f, 0.f, 0.f, 0.f);
  }
  __syncthreads();

  float acc[16];
  if (t < 128) {
    const float binit = b_cond[t] + (t < 64 ? 1.0f : 0.0f);
#pragma unroll
    for (int j = 0; j < 16; ++j) acc[j] = binit;
    for (int k4 = 0; k4 < 64; ++k4) {
      const float w0 = W_cond[(k4 * 4 + 0) * 128 + t];
      const float w1 = W_cond[(k4 * 4 + 1) * 128 + t];
      const float w2 = W_cond[(k4 * 4 + 2) * 128 + t];
      const float w3 = W_cond[(k4 * 4 + 3) * 128 + t];
#pragma unroll
      for (int j = 0; j < 16; ++j) {
        const float4 v = *(const float4*)&cond_lds[j][k4 * 4];
        acc[j] = fmaf(v.w, w3, fmaf(v.z, w2, fmaf(v.y, w1, fmaf(v.x, w0, acc[j]))));
      }
    }
#pragma unroll
    for (int j = 0; j < 16; ++j) gb_lds[j][t] = acc[j];
  } else {
    const int c = t - 128;
    const float binit = b_film[c];
#pragma unroll
    for (int j = 0; j < 16; ++j) acc[j] = binit;
    for (int k4 = 0; k4 < 32; ++k4) {
      const float w0 = W_film[(k4 * 4 + 0) * 64 + c];
      const float w1 = W_film[(k4 * 4 + 1) * 64 + c];
      const float w2 = W_film[(k4 * 4 + 2) * 64 + c];
      const float w3 = W_film[(k4 * 4 + 3) * 64 + c];
#pragma unroll
      for (int j = 0; j < 16; ++j) {
        const float4 v = *(const float4*)&nf_lds[j][k4 * 4];
        acc[j] = fmaf(v.w, w3, fmaf(v.z, w2, fmaf(v.y, w1, fmaf(v.x, w0, acc[j]))));
      }
    }
    // LayerNorm over the 64 columns (one per lane of wave 2)
#pragma unroll
    for (int j = 0; j < 16; ++j) {
      float s = acc[j];
      float q = acc[j] * acc[j];
#pragma unroll
      for (int off = 32; off >= 1; off >>= 1) {
        s += __shfl_xor(s, off, 64);
        q += __shfl_xor(q, off, 64);
      }
      const float mu = s * (1.0f / 64.0f);
      const float var = q * (1.0f / 64.0f) - mu * mu;
      acc[j] = (acc[j] - mu) * rsqrtf(var + EPSV);
    }
  }
  __syncthreads();
  if (t >= 128) {
    const int c = t - 128;
#pragma unroll
    for (int j = 0; j < 16; ++j) {
      if (j < rows) {
        const float g = gb_lds[j][c];          // gamma (already +1)
        const float b = gb_lds[j][64 + c];     // beta
        const float hv = fmaf(g, acc[j], b);
        h[(size_t)(n0 + j) * 64 + c] = fmaxf(hv, 0.0f);
      }
    }
  }
}

// ---------------- edge pipeline ----------------
// per edge e: ep = tanh(edge_feats[mirror[e]] @ W_edge + b_edge) * ew[e]
//             out[dst[e]] += h[src[e]] * ep         (atomic scatter-add)
// one wave per edge (grid-stride); W_edge column held in 64 VGPRs per lane.
__global__ __launch_bounds__(256) void edge_kernel(
    const float* __restrict__ edge_feats, const float* __restrict__ edge_weights,
    const int* __restrict__ src, const int* __restrict__ dst,
    const int* __restrict__ mirror,
    const float* __restrict__ W_edge, const float* __restrict__ b_edge,
    const float* __restrict__ h, float* __restrict__ out, int E)
{
  __shared__ __align__(16) float sh[4][64];
  const int lane = threadIdx.x & 63;
  const int wid = threadIdx.x >> 6;
  float Wcol[64];
#pragma unroll
  for (int k = 0; k < 64; ++k) Wcol[k] = W_edge[k * 64 + lane];
  const float be = b_edge[lane];
  const int nwaves = gridDim.x * 4;
  for (int e = blockIdx.x * 4 + wid; e < E; e += nwaves) {
    const int m = mirror[e];
    const int s = src[e];
    const int d = dst[e];
    const float w = edge_weights[e];
    const float ef = edge_feats[(size_t)m * 64 + lane];
    const float hs = h[(size_t)s * 64 + lane];
    sh[wid][lane] = ef;
    float acc = be;
    const float4* s4 = (const float4*)sh[wid];
#pragma unroll
    for (int k4 = 0; k4 < 16; ++k4) {
      const float4 v = s4[k4];
      acc = fmaf(v.x, Wcol[4 * k4 + 0], acc);
      acc = fmaf(v.y, Wcol[4 * k4 + 1], acc);
      acc = fmaf(v.z, Wcol[4 * k4 + 2], acc);
      acc = fmaf(v.w, Wcol[4 * k4 + 3], acc);
    }
    // tanh(acc) = 1 - 2/(exp(2*acc)+1); __expf handles +/-inf limits correctly
    const float p = (1.0f - 2.0f / (__expf(2.0f * acc) + 1.0f)) * w;
    atomicAdd(&out[(size_t)d * 64 + lane], hs * p);
  }
}

extern "C" void kernel_launch(void* const* d_in, const int* in_sizes, int n_in,
                              void* d_out, int out_size, void* d_ws, size_t ws_size,
                              hipStream_t stream) {
  const float* node_feats   = (const float*)d_in[0];
  const float* edge_feats   = (const float*)d_in[1];
  const float* cond         = (const float*)d_in[2];
  const float* edge_weights = (const float*)d_in[3];
  const int*   src          = (const int*)d_in[4];
  const int*   dst          = (const int*)d_in[5];
  const int*   mirror       = (const int*)d_in[6];
  const float* W_edge       = (const float*)d_in[7];
  const float* b_edge       = (const float*)d_in[8];
  const float* W_cond       = (const float*)d_in[9];
  const float* b_cond       = (const float*)d_in[10];
  const float* W_film       = (const float*)d_in[11];
  const float* b_film       = (const float*)d_in[12];
  const int N = in_sizes[0] / 128;
  const int E = in_sizes[4];
  float* h = (float*)d_ws;   // N*64 floats = 12.8 MB scratch

  hipMemsetAsync(d_out, 0, (size_t)out_size * sizeof(float), stream);
  node_kernel<<<(N + 15) / 16, 192, 0, stream>>>(
      node_feats, cond, W_cond, b_cond, W_film, b_film, h, N);
  edge_kernel<<<2048, 256, 0, stream>>>(
      edge_feats, edge_weights, src, dst, mirror, W_edge, b_edge, h,
      (float*)d_out, E);
}

// Round 2
// 294.586 us; speedup vs baseline: 1.2059x; 1.2059x over previous
//
#include <hip/hip_runtime.h>
#include <hip/hip_bf16.h>

#define EPSV 1e-5f

typedef __attribute__((ext_vector_type(8))) short bf16x8;
typedef __attribute__((ext_vector_type(4))) float f32x4;

static __device__ __forceinline__ short f2bf(float f) {
  return __builtin_bit_cast(short, __float2bfloat16(f));
}

// ---------------- node pipeline ----------------
// h = relu((1 + gamma(cond)) * LN(node_feats @ W_film + b_film) + beta(cond))
__global__ __launch_bounds__(192) void node_kernel(
    const float* __restrict__ node_feats, const float* __restrict__ cond,
    const float* __restrict__ W_cond, const float* __restrict__ b_cond,
    const float* __restrict__ W_film, const float* __restrict__ b_film,
    float* __restrict__ h, int N)
{
  __shared__ __align__(16) float cond_lds[16][256];
  __shared__ __align__(16) float nf_lds[16][128];
  __shared__ __align__(16) float gb_lds[16][128];
  const int t = threadIdx.x;
  const int n0 = blockIdx.x * 16;
  const int rows = min(16, N - n0);

  { // stage cond tile (16x256) and nf tile (16x128) as float4
    const float4* c4 = (const float4*)(cond + (size_t)n0 * 256);
    float4* sc = (float4*)&cond_lds[0][0];
    const int climit = rows * 64;
    for (int i = t; i < 16 * 64; i += 192)
      sc[i] = (i < climit) ? c4[i] : make_float4(0.f, 0.f, 0.f, 0.f);
    const float4* n4 = (const float4*)(node_feats + (size_t)n0 * 128);
    float4* sn = (float4*)&nf_lds[0][0];
    const int nlimit = rows * 32;
    for (int i = t; i < 16 * 32; i += 192)
      sn[i] = (i < nlimit) ? n4[i] : make_float4(0.f, 0.f, 0.f, 0.f);
  }
  __syncthreads();

  float acc[16];
  if (t < 128) {
    const float binit = b_cond[t] + (t < 64 ? 1.0f : 0.0f);
#pragma unroll
    for (int j = 0; j < 16; ++j) acc[j] = binit;
    for (int k4 = 0; k4 < 64; ++k4) {
      const float w0 = W_cond[(k4 * 4 + 0) * 128 + t];
      const float w1 = W_cond[(k4 * 4 + 1) * 128 + t];
      const float w2 = W_cond[(k4 * 4 + 2) * 128 + t];
      const float w3 = W_cond[(k4 * 4 + 3) * 128 + t];
#pragma unroll
      for (int j = 0; j < 16; ++j) {
        const float4 v = *(const float4*)&cond_lds[j][k4 * 4];
        acc[j] = fmaf(v.w, w3, fmaf(v.z, w2, fmaf(v.y, w1, fmaf(v.x, w0, acc[j]))));
      }
    }
#pragma unroll
    for (int j = 0; j < 16; ++j) gb_lds[j][t] = acc[j];
  } else {
    const int c = t - 128;
    const float binit = b_film[c];
#pragma unroll
    for (int j = 0; j < 16; ++j) acc[j] = binit;
    for (int k4 = 0; k4 < 32; ++k4) {
      const float w0 = W_film[(k4 * 4 + 0) * 64 + c];
      const float w1 = W_film[(k4 * 4 + 1) * 64 + c];
      const float w2 = W_film[(k4 * 4 + 2) * 64 + c];
      const float w3 = W_film[(k4 * 4 + 3) * 64 + c];
#pragma unroll
      for (int j = 0; j < 16; ++j) {
        const float4 v = *(const float4*)&nf_lds[j][k4 * 4];
        acc[j] = fmaf(v.w, w3, fmaf(v.z, w2, fmaf(v.y, w1, fmaf(v.x, w0, acc[j]))));
      }
    }
#pragma unroll
    for (int j = 0; j < 16; ++j) {
      float s = acc[j];
      float q = acc[j] * acc[j];
#pragma unroll
      for (int off = 32; off >= 1; off >>= 1) {
        s += __shfl_xor(s, off, 64);
        q += __shfl_xor(q, off, 64);
      }
      const float mu = s * (1.0f / 64.0f);
      const float var = q * (1.0f / 64.0f) - mu * mu;
      acc[j] = (acc[j] - mu) * rsqrtf(var + EPSV);
    }
  }
  __syncthreads();
  if (t >= 128) {
    const int c = t - 128;
#pragma unroll
    for (int j = 0; j < 16; ++j) {
      if (j < rows) {
        const float g = gb_lds[j][c];          // gamma (already +1)
        const float b = gb_lds[j][64 + c];     // beta
        const float hv = fmaf(g, acc[j], b);
        h[(size_t)(n0 + j) * 64 + c] = fmaxf(hv, 0.0f);
      }
    }
  }
}

// ---------------- edge pipeline (MFMA, 16 edges per wave-tile) ----------------
// ep = tanh(edge_feats[mirror[e]] @ W_edge + b_edge) * ew[e]
// out[dst[e]] += h[src[e]] * ep
// A-fragment gathered straight from global (no LDS): lane l -> row l&15,
// k = (l>>4)*8..+7.  B (W_edge) in 8 reg fragments. C/D: col=l&15, row=(l>>4)*4+reg.
__global__ __launch_bounds__(256) void edge_kernel(
    const float* __restrict__ edge_feats, const float* __restrict__ edge_weights,
    const int* __restrict__ src, const int* __restrict__ dst,
    const int* __restrict__ mirror,
    const float* __restrict__ W_edge, const float* __restrict__ b_edge,
    const float* __restrict__ h, float* __restrict__ out, int E)
{
  const int lane = threadIdx.x & 63;
  const int r16  = lane & 15;
  const int kb   = lane >> 4;
  const int gwid   = (int)((blockIdx.x * blockDim.x + threadIdx.x) >> 6);
  const int nwaves = (int)((gridDim.x * blockDim.x) >> 6);

  // B fragments: W_edge[k][n] (k-major).  bfr[nb][ks], k = ks*32 + kb*8 + j,
  // n = nb*16 + r16.  32 VGPRs total, loaded once per wave.
  bf16x8 bfr[4][2];
#pragma unroll
  for (int nb = 0; nb < 4; ++nb)
#pragma unroll
    for (int ks = 0; ks < 2; ++ks)
#pragma unroll
      for (int j = 0; j < 8; ++j) {
        const int k = ks * 32 + kb * 8 + j;
        bfr[nb][ks][j] = f2bf(W_edge[k * 64 + nb * 16 + r16]);
      }
  float bb[4];
#pragma unroll
  for (int nb = 0; nb < 4; ++nb) bb[nb] = b_edge[nb * 16 + r16];

  const int ntiles = (E + 15) >> 4;
  for (int t = gwid; t < ntiles; t += nwaves) {
    const int e0 = t << 4;
    // per-row meta (row = r16); clamp tail, zero ew so OOB rows contribute 0
    const int  er = min(e0 + r16, E - 1);
    const int  sv = src[er];
    const int  dv = dst[er];
    const float wv = (e0 + r16 < E) ? edge_weights[er] : 0.0f;
    const int  mv = mirror[er];

    // A gather: two k-steps, 2 aligned float4 each
    const float* arow = edge_feats + (size_t)mv * 64 + kb * 8;
    const f32x4 a0 = *(const f32x4*)(arow);
    const f32x4 a1 = *(const f32x4*)(arow + 4);
    const f32x4 a2 = *(const f32x4*)(arow + 32);
    const f32x4 a3 = *(const f32x4*)(arow + 36);

    // epilogue operands, issued early to hide gather latency
    int   dj[4];
    float ewj[4];
    float hv[4][4];
#pragma unroll
    for (int j = 0; j < 4; ++j) {
      const int row = kb * 4 + j;                 // C-row this reg maps to
      const int sj = __shfl(sv, row, 64);
      dj[j]  = __shfl(dv, row, 64);
      ewj[j] = __shfl(wv, row, 64);
      const float* hrow = h + (size_t)sj * 64 + r16;
#pragma unroll
      for (int nb = 0; nb < 4; ++nb) hv[j][nb] = hrow[nb * 16];
    }

    // convert A to bf16 fragments
    bf16x8 af0, af1;
#pragma unroll
    for (int j = 0; j < 4; ++j) {
      af0[j]     = f2bf(a0[j]);
      af0[j + 4] = f2bf(a1[j]);
      af1[j]     = f2bf(a2[j]);
      af1[j + 4] = f2bf(a3[j]);
    }

    f32x4 c[4];
#pragma unroll
    for (int nb = 0; nb < 4; ++nb) c[nb] = (f32x4){0.f, 0.f, 0.f, 0.f};
#pragma unroll
    for (int nb = 0; nb < 4; ++nb) {
      c[nb] = __builtin_amdgcn_mfma_f32_16x16x32_bf16(af0, bfr[nb][0], c[nb], 0, 0, 0);
      c[nb] = __builtin_amdgcn_mfma_f32_16x16x32_bf16(af1, bfr[nb][1], c[nb], 0, 0, 0);
    }

    // epilogue: tanh, scale, gather-multiply, scatter-add
#pragma unroll
    for (int j = 0; j < 4; ++j) {
#pragma unroll
      for (int nb = 0; nb < 4; ++nb) {
        const float s = c[nb][j] + bb[nb];
        const float p = (1.0f - 2.0f / (__expf(2.0f * s) + 1.0f)) * ewj[j];
        atomicAdd(&out[(size_t)dj[j] * 64 + nb * 16 + r16], p * hv[j][nb]);
      }
    }
  }
}

extern "C" void kernel_launch(void* const* d_in, const int* in_sizes, int n_in,
                              void* d_out, int out_size, void* d_ws, size_t ws_size,
                              hipStream_t stream) {
  const float* node_feats   = (const float*)d_in[0];
  const float* edge_feats   = (const float*)d_in[1];
  const float* cond         = (const float*)d_in[2];
  const float* edge_weights = (const float*)d_in[3];
  const int*   src          = (const int*)d_in[4];
  const int*   dst          = (const int*)d_in[5];
  const int*   mirror       = (const int*)d_in[6];
  const float* W_edge       = (const float*)d_in[7];
  const float* b_edge       = (const float*)d_in[8];
  const float* W_cond       = (const float*)d_in[9];
  const float* b_cond       = (const float*)d_in[10];
  const float* W_film       = (const float*)d_in[11];
  const float* b_film       = (const float*)d_in[12];
  const int N = in_sizes[0] / 128;
  const int E = in_sizes[4];
  float* h = (float*)d_ws;   // N*64 floats = 12.8 MB scratch

  hipMemsetAsync(d_out, 0, (size_t)out_size * sizeof(float), stream);
  node_kernel<<<(N + 15) / 16, 192, 0, stream>>>(
      node_feats, cond, W_cond, b_cond, W_film, b_film, h, N);
  edge_kernel<<<2048, 256, 0, stream>>>(
      edge_feats, edge_weights, src, dst, mirror, W_edge, b_edge, h,
      (float*)d_out, E);
}